// Round 1
// baseline (204.771 us; speedup 1.0000x reference)
//
#include <hip/hip_runtime.h>
#include <cstdint>
#include <cstddef>

// Problem constants
#define BQ 8
#define CDIM 64
#define HQ 64
#define WQ 64
#define KDIM 512
#define N_SIG 32768   // B*H*W
#define S_NNZ 4

// d_out float offsets (outputs concatenated flat in return order)
#define DIFF_ENC_OFF 2097152
#define DIFF_DICT_OFF 2097153
#define IDS_OFF 2097154
#define NUM_STEPS_OFF 18874370
#define MEAN_D_OFF 18874371
#define MEAN_Z_OFF 18874372
#define NORM_Z_OFF 18874373
#define TOP_PCT_OFF 18874374
#define NUM_ZEROS_OFF 18874375

// ws float offsets
// [0..8)   : 4 doubles: sumAbsD, sumAbsZ, sumSq, (pad)
// [8..16)  : 8 ints: hist[5], pad
#define WS_DN 16
#define WS_DNT 32784
#define WS_G 65552
#define WS_WG 327696   // float4 per signal (gamma)
#define WS_WI 458768   // int4 per signal (idx)

__global__ __launch_bounds__(64) void k_zero_acc(float* ws) {
  int t = threadIdx.x;
  if (t < 16) ((unsigned int*)ws)[t] = 0u;
}

// ---- dictionary normalization ----
__global__ __launch_bounds__(256) void k_dict(const float* __restrict__ D,
                                              float* __restrict__ Dn,
                                              float* __restrict__ DnT,
                                              double* __restrict__ accs) {
  int k = blockIdx.x * 256 + threadIdx.x;  // 0..511 (grid = 2 blocks)
  float ss = 0.f;
  for (int c = 0; c < CDIM; ++c) {
    float v = D[c * KDIM + k];
    ss = fmaf(v, v, ss);
  }
  float nrm = sqrtf(ss);
  float sabs = 0.f;
  for (int c = 0; c < CDIM; ++c) {
    float v = D[c * KDIM + k] / nrm;
    Dn[c * KDIM + k] = v;
    DnT[k * CDIM + c] = v;
    sabs += fabsf(v);
  }
#pragma unroll
  for (int off = 32; off >= 1; off >>= 1) sabs += __shfl_xor(sabs, off);
  if ((threadIdx.x & 63) == 0) atomicAdd(&accs[0], (double)sabs);
}

// ---- Gram matrix G = Dn^T Dn ----
__global__ __launch_bounds__(256) void k_gram(const float* __restrict__ Dn,
                                              float* __restrict__ G) {
  int g = blockIdx.x * 256 + threadIdx.x;  // grid = 1024 blocks
  int i = g >> 9, j = g & 511;
  float s = 0.f;
#pragma unroll 8
  for (int c = 0; c < CDIM; ++c) s = fmaf(Dn[c * KDIM + i], Dn[c * KDIM + j], s);
  G[(size_t)i * KDIM + j] = s;
}

// ---- alpha0 = X_flat @ Dn  (M=32768, K=64, N=512), 64x64 tiles ----
__global__ __launch_bounds__(256) void k_alpha0(const float* __restrict__ X,
                                                const float* __restrict__ Dn,
                                                float* __restrict__ A0) {
  __shared__ float Xs[64 * 65];
  __shared__ float Dns[64 * 64];
  int tid = threadIdx.x;
  int mt = blockIdx.x >> 3, nt = blockIdx.x & 7;
  int b = mt >> 6, h = mt & 63;
  int w = tid & 63, cq = tid >> 6;
#pragma unroll
  for (int p = 0; p < 16; ++p) {
    int c = p * 4 + cq;
    Xs[w * 65 + c] = X[(((size_t)b * CDIM + c) * HQ + h) * WQ + w];
    Dns[c * 64 + w] = Dn[(size_t)c * KDIM + nt * 64 + w];
  }
  __syncthreads();
  int ty = tid >> 4, tx = tid & 15;
  float acc[4][4] = {};
  for (int c = 0; c < 64; ++c) {
    float av[4];
#pragma unroll
    for (int i = 0; i < 4; ++i) av[i] = Xs[(ty * 4 + i) * 65 + c];
    float4 bv = *(const float4*)&Dns[c * 64 + tx * 4];
#pragma unroll
    for (int i = 0; i < 4; ++i) {
      acc[i][0] = fmaf(av[i], bv.x, acc[i][0]);
      acc[i][1] = fmaf(av[i], bv.y, acc[i][1]);
      acc[i][2] = fmaf(av[i], bv.z, acc[i][2]);
      acc[i][3] = fmaf(av[i], bv.w, acc[i][3]);
    }
  }
  size_t n0 = (size_t)mt * 64;
#pragma unroll
  for (int i = 0; i < 4; ++i) {
    float4 st = make_float4(acc[i][0], acc[i][1], acc[i][2], acc[i][3]);
    *(float4*)&A0[(n0 + ty * 4 + i) * KDIM + nt * 64 + tx * 4] = st;
  }
}

// ---- OMP core helpers ----
__device__ __forceinline__ float wave_get(const float (&v)[8], int k) {
  int src = k >> 3, m = k & 7;
  float x = v[0];
#pragma unroll
  for (int mm = 1; mm < 8; ++mm)
    if (m == mm) x = v[mm];
  return __shfl(x, src);
}

template <int SZ>
__device__ __forceinline__ void solve_sz(const float (&gs)[4][4], const float (&rhs)[4],
                                         float (&gamma)[4]) {
  double M[SZ][SZ];
  double y[SZ];
#pragma unroll
  for (int a = 0; a < SZ; ++a) {
    y[a] = (double)rhs[a];
#pragma unroll
    for (int b = 0; b < SZ; ++b) M[a][b] = (double)gs[a][b] + (a == b ? 1e-7 : 0.0);
  }
#pragma unroll
  for (int p = 0; p < SZ; ++p) {
    double inv = 1.0 / M[p][p];
#pragma unroll
    for (int r = p + 1; r < SZ; ++r) {
      double f = M[r][p] * inv;
#pragma unroll
      for (int c = p; c < SZ; ++c) M[r][c] -= f * M[p][c];
      y[r] -= f * y[p];
    }
  }
#pragma unroll
  for (int r = SZ - 1; r >= 0; --r) {
    double t = y[r];
#pragma unroll
    for (int c = r + 1; c < SZ; ++c) t -= M[r][c] * (double)gamma[c];
    gamma[r] = (float)(t / M[r][r]);
  }
}

template <int K>
__device__ __forceinline__ void omp_step(int lane, const float* __restrict__ G,
                                         float (&a0)[8], float (&al)[8], float (&Grow)[4][8],
                                         float (&gs)[4][4], float (&rhs)[4], int (&idx)[4],
                                         float (&gamma)[4]) {
  // argmax |al| (first-occurrence wins, i.e. lowest element index)
  float bv = -1.0f;
  int bk = 0;
#pragma unroll
  for (int m = 0; m < 8; ++m) {
    float v = fabsf(al[m]);
    int ke = lane * 8 + m;
    if (v > bv) { bv = v; bk = ke; }
  }
#pragma unroll
  for (int off = 32; off >= 1; off >>= 1) {
    float ov = __shfl_xor(bv, off);
    int ok = __shfl_xor(bk, off);
    if (ov > bv || (ov == bv && ok < bk)) { bv = ov; bk = ok; }
  }
  idx[K] = bk;
  const float4* gp = (const float4*)(G + (size_t)bk * KDIM + lane * 8);
  float4 r0 = gp[0], r1 = gp[1];
  Grow[K][0] = r0.x; Grow[K][1] = r0.y; Grow[K][2] = r0.z; Grow[K][3] = r0.w;
  Grow[K][4] = r1.x; Grow[K][5] = r1.y; Grow[K][6] = r1.z; Grow[K][7] = r1.w;
#pragma unroll
  for (int b = 0; b < K; ++b) {
    float v = wave_get(Grow[K], idx[b]);
    gs[K][b] = v;
    gs[b][K] = v;
  }
  gs[K][K] = wave_get(Grow[K], idx[K]);
  rhs[K] = wave_get(a0, idx[K]);
  solve_sz<K + 1>(gs, rhs, gamma);
  if (K < 3) {
#pragma unroll
    for (int m = 0; m < 8; ++m) {
      float acc = a0[m];
#pragma unroll
      for (int a = 0; a <= K; ++a) acc = fmaf(-gamma[a], Grow[a][m], acc);
      al[m] = acc;
    }
  }
}

// ---- OMP main: one wave per signal ----
__global__ __launch_bounds__(256) void k_omp(const float* __restrict__ A0,
                                             const float* __restrict__ G,
                                             float4* __restrict__ wg, int4* __restrict__ wi) {
  int tid = threadIdx.x;
  int lane = tid & 63, wv = tid >> 6;
  int n = blockIdx.x * 4 + wv;  // grid = 8192 blocks
  const float4* ap = (const float4*)(A0 + (size_t)n * KDIM + lane * 8);
  float4 v0 = ap[0], v1 = ap[1];
  float a0[8] = {v0.x, v0.y, v0.z, v0.w, v1.x, v1.y, v1.z, v1.w};
  float al[8];
#pragma unroll
  for (int m = 0; m < 8; ++m) al[m] = a0[m];
  float Grow[4][8];
  float gs[4][4];
  float rhs[4];
  int idx[4];
  float gamma[4];
  omp_step<0>(lane, G, a0, al, Grow, gs, rhs, idx, gamma);
  omp_step<1>(lane, G, a0, al, Grow, gs, rhs, idx, gamma);
  omp_step<2>(lane, G, a0, al, Grow, gs, rhs, idx, gamma);
  omp_step<3>(lane, G, a0, al, Grow, gs, rhs, idx, gamma);
  if (lane == 0) {
    wg[n] = make_float4(gamma[0], gamma[1], gamma[2], gamma[3]);
    wi[n] = make_int4(idx[0], idx[1], idx[2], idx[3]);
  }
}

// ---- epilogue: per (b,h) row of 64 signals ----
__global__ __launch_bounds__(256) void k_epi(const float* __restrict__ X,
                                             const float* __restrict__ DnT,
                                             const float4* __restrict__ wg,
                                             const int4* __restrict__ wi,
                                             float* __restrict__ out, double* __restrict__ accs,
                                             int* __restrict__ hist) {
  __shared__ int sIdx[64][4];
  __shared__ float sKg[64][4];
  __shared__ float q[64 * 65];
  __shared__ float red[4];
  int tid = threadIdx.x;
  int bh = blockIdx.x;  // grid = 512
  int b = bh >> 6, h = bh & 63;

  if (tid < 64) {
    int w = tid;
    int n = bh * 64 + w;
    int4 iv = wi[n];
    float4 gv = wg[n];
    bool k0 = (iv.x != iv.y) && (iv.x != iv.z) && (iv.x != iv.w);
    bool k1 = (iv.y != iv.z) && (iv.y != iv.w);
    bool k2 = (iv.z != iv.w);
    float g0 = k0 ? gv.x : 0.f;
    float g1 = k1 ? gv.y : 0.f;
    float g2 = k2 ? gv.z : 0.f;
    float g3 = gv.w;
    sIdx[w][0] = iv.x; sIdx[w][1] = iv.y; sIdx[w][2] = iv.z; sIdx[w][3] = iv.w;
    sKg[w][0] = g0; sKg[w][1] = g1; sKg[w][2] = g2; sKg[w][3] = g3;
    int nz = (int)(k0 && gv.x != 0.f) + (int)(k1 && gv.y != 0.f) +
             (int)(k2 && gv.z != 0.f) + (int)(gv.w != 0.f);
    float sabs = (k0 ? fabsf(gv.x) : 0.f) + (k1 ? fabsf(gv.y) : 0.f) +
                 (k2 ? fabsf(gv.z) : 0.f) + fabsf(gv.w);
    float s = sabs;
#pragma unroll
    for (int off = 32; off >= 1; off >>= 1) s += __shfl_xor(s, off);
#pragma unroll
    for (int v = 0; v < 5; ++v) {
      unsigned long long m = __ballot(nz == v);
      if (tid == 0) {
        int c = (int)__popcll(m);
        if (c) atomicAdd(&hist[v], c);
      }
    }
    if (tid == 0) atomicAdd(&accs[1], (double)s);
  }
  __syncthreads();

  int w2 = tid & 63, p = tid >> 6, c0 = p * 16;
  float acc[16] = {};
#pragma unroll
  for (int s = 0; s < 4; ++s) {
    int ks = sIdx[w2][s];
    float g = sKg[w2][s];
    const float4* dp = (const float4*)(DnT + (size_t)ks * CDIM + c0);
#pragma unroll
    for (int i4 = 0; i4 < 4; ++i4) {
      float4 d = dp[i4];
      acc[i4 * 4 + 0] = fmaf(g, d.x, acc[i4 * 4 + 0]);
      acc[i4 * 4 + 1] = fmaf(g, d.y, acc[i4 * 4 + 1]);
      acc[i4 * 4 + 2] = fmaf(g, d.z, acc[i4 * 4 + 2]);
      acc[i4 * 4 + 3] = fmaf(g, d.w, acc[i4 * 4 + 3]);
    }
  }
#pragma unroll
  for (int i = 0; i < 16; ++i) q[(c0 + i) * 65 + w2] = acc[i];
  __syncthreads();

  float sumsq = 0.f;
#pragma unroll
  for (int pass = 0; pass < 16; ++pass) {
    int c = pass * 4 + p;
    float qv = q[c * 65 + w2];
    size_t off = (((size_t)b * CDIM + c) * HQ + h) * WQ + w2;
    float xv = X[off];
    float d = qv - xv;
    sumsq = fmaf(d, d, sumsq);
    out[off] = qv;
  }

  // dense ids write (replaces memset + scatter)
  {
    int i0 = sIdx[w2][0], i1 = sIdx[w2][1], i2 = sIdx[w2][2], i3 = sIdx[w2][3];
    float g0 = sKg[w2][0], g1 = sKg[w2][1], g2 = sKg[w2][2], g3 = sKg[w2][3];
    float* ids = out + IDS_OFF;
    for (int kk = 0; kk < 128; ++kk) {
      int k = kk * 4 + p;
      float v = 0.f;
      v = (k == i0) ? g0 : v;
      v = (k == i1) ? g1 : v;
      v = (k == i2) ? g2 : v;
      v = (k == i3) ? g3 : v;
      ids[(((size_t)b * KDIM + k) * HQ + h) * WQ + w2] = v;
    }
  }

#pragma unroll
  for (int off = 32; off >= 1; off >>= 1) sumsq += __shfl_xor(sumsq, off);
  if ((tid & 63) == 0) red[tid >> 6] = sumsq;
  __syncthreads();
  if (tid == 0) atomicAdd(&accs[2], (double)(red[0] + red[1] + red[2] + red[3]));
}

// ---- finalize scalars ----
__global__ __launch_bounds__(64) void k_final(const double* __restrict__ accs,
                                              const int* __restrict__ hist,
                                              float* __restrict__ out) {
  if (threadIdx.x == 0) {
    double sumAbsD = accs[0], sumAbsZ = accs[1], sumSq = accs[2];
    float diff = (float)(sumSq / 2097152.0);
    out[DIFF_ENC_OFF] = diff;
    out[DIFF_DICT_OFF] = diff;
    out[NUM_STEPS_OFF] = 4.0f;
    out[MEAN_D_OFF] = (float)(sumAbsD / 32768.0);
    out[MEAN_Z_OFF] = (float)(sumAbsZ / 16777216.0);
    int h0 = hist[0], h1 = hist[1], h2 = hist[2], h3 = hist[3], h4 = hist[4];
    out[NORM_Z_OFF] = (float)((double)(h1 + 2 * h2 + 3 * h3 + 4 * h4) / 32768.0);
    int cum = 0, res = 0;
    for (int v = 4; v >= 0; --v) {
      cum += hist[v];
      if (cum >= 327) { res = v; break; }
    }
    out[TOP_PCT_OFF] = (float)res;
    out[NUM_ZEROS_OFF] = (float)h0;
  }
}

extern "C" void kernel_launch(void* const* d_in, const int* in_sizes, int n_in,
                              void* d_out, int out_size, void* d_ws, size_t ws_size,
                              hipStream_t stream) {
  (void)in_sizes; (void)n_in; (void)out_size; (void)ws_size;
  const float* X = (const float*)d_in[0];    // [8,64,64,64]
  const float* D = (const float*)d_in[1];    // [64,512]
  float* out = (float*)d_out;
  float* W = (float*)d_ws;
  double* accs = (double*)d_ws;
  int* hist = (int*)W + 8;
  float* Dn = W + WS_DN;
  float* DnT = W + WS_DNT;
  float* G = W + WS_G;
  float4* wgam = (float4*)(W + WS_WG);
  int4* widx = (int4*)(W + WS_WI);
  float* A0 = out;  // stage alpha0 in d_out[0 .. 16,777,216) — overwritten later

  hipLaunchKernelGGL(k_zero_acc, dim3(1), dim3(64), 0, stream, W);
  hipLaunchKernelGGL(k_dict, dim3(2), dim3(256), 0, stream, D, Dn, DnT, accs);
  hipLaunchKernelGGL(k_gram, dim3(1024), dim3(256), 0, stream, Dn, G);
  hipLaunchKernelGGL(k_alpha0, dim3(4096), dim3(256), 0, stream, X, Dn, A0);
  hipLaunchKernelGGL(k_omp, dim3(8192), dim3(256), 0, stream, A0, G, wgam, widx);
  hipLaunchKernelGGL(k_epi, dim3(512), dim3(256), 0, stream, X, DnT, wgam, widx, out, accs, hist);
  hipLaunchKernelGGL(k_final, dim3(1), dim3(64), 0, stream, accs, hist, out);
}

// Round 2
// 190.175 us; speedup vs baseline: 1.0767x; 1.0767x over previous
//
#include <hip/hip_runtime.h>
#include <cstdint>
#include <cstddef>

// Problem constants
#define BQ 8
#define CDIM 64
#define HQ 64
#define WQ 64
#define KDIM 512
#define N_SIG 32768   // B*H*W
#define S_NNZ 4

// d_out float offsets (outputs concatenated flat in return order)
#define DIFF_ENC_OFF 2097152
#define DIFF_DICT_OFF 2097153
#define IDS_OFF 2097154
#define NUM_STEPS_OFF 18874370
#define MEAN_D_OFF 18874371
#define MEAN_Z_OFF 18874372
#define NORM_Z_OFF 18874373
#define TOP_PCT_OFF 18874374
#define NUM_ZEROS_OFF 18874375

// ws float offsets
// [0..8)   : 4 doubles: sumAbsD, sumAbsZ, sumSq, (pad)
// [8..16)  : ints: hist[5], pad
#define WS_DN 16
#define WS_DNT 32784
#define WS_G 65552
#define WS_WG 327696   // float4 per signal (deduped gamma)
#define WS_WI 458768   // int4 per signal (idx)

// ---- dictionary normalization + accumulator zeroing (single block) ----
__global__ __launch_bounds__(512) void k_dict(const float* __restrict__ D,
                                              float* __restrict__ Dn,
                                              float* __restrict__ DnT,
                                              float* __restrict__ W) {
  int tid = threadIdx.x;
  if (tid < 16) ((unsigned int*)W)[tid] = 0u;
  __syncthreads();
  double* accs = (double*)W;
  int k = tid;  // 512 threads, one column each
  float ss = 0.f;
  for (int c = 0; c < CDIM; ++c) {
    float v = D[c * KDIM + k];
    ss = fmaf(v, v, ss);
  }
  float nrm = sqrtf(ss);
  float sabs = 0.f;
  for (int c = 0; c < CDIM; ++c) {
    float v = D[c * KDIM + k] / nrm;
    Dn[c * KDIM + k] = v;
    DnT[k * CDIM + c] = v;
    sabs += fabsf(v);
  }
#pragma unroll
  for (int off = 32; off >= 1; off >>= 1) sabs += __shfl_xor(sabs, off);
  if ((tid & 63) == 0) atomicAdd(&accs[0], (double)sabs);
}

// ---- Gram matrix G = Dn^T Dn ----
__global__ __launch_bounds__(256) void k_gram(const float* __restrict__ Dn,
                                              float* __restrict__ G) {
  int g = blockIdx.x * 256 + threadIdx.x;  // grid = 1024 blocks
  int i = g >> 9, j = g & 511;
  float s = 0.f;
#pragma unroll 8
  for (int c = 0; c < CDIM; ++c) s = fmaf(Dn[c * KDIM + i], Dn[c * KDIM + j], s);
  G[(size_t)i * KDIM + j] = s;
}

// ---- alpha0 = X_flat @ Dn  (M=32768, K=64, N=512), 64x64 tiles ----
__global__ __launch_bounds__(256) void k_alpha0(const float* __restrict__ X,
                                                const float* __restrict__ Dn,
                                                float* __restrict__ A0) {
  __shared__ float Xs[64 * 65];
  __shared__ float Dns[64 * 64];
  int tid = threadIdx.x;
  int mt = blockIdx.x >> 3, nt = blockIdx.x & 7;
  int b = mt >> 6, h = mt & 63;
  int w = tid & 63, cq = tid >> 6;
#pragma unroll
  for (int p = 0; p < 16; ++p) {
    int c = p * 4 + cq;
    Xs[w * 65 + c] = X[(((size_t)b * CDIM + c) * HQ + h) * WQ + w];
    Dns[c * 64 + w] = Dn[(size_t)c * KDIM + nt * 64 + w];
  }
  __syncthreads();
  int ty = tid >> 4, tx = tid & 15;
  float acc[4][4] = {};
  for (int c = 0; c < 64; ++c) {
    float av[4];
#pragma unroll
    for (int i = 0; i < 4; ++i) av[i] = Xs[(ty * 4 + i) * 65 + c];
    float4 bv = *(const float4*)&Dns[c * 64 + tx * 4];
#pragma unroll
    for (int i = 0; i < 4; ++i) {
      acc[i][0] = fmaf(av[i], bv.x, acc[i][0]);
      acc[i][1] = fmaf(av[i], bv.y, acc[i][1]);
      acc[i][2] = fmaf(av[i], bv.z, acc[i][2]);
      acc[i][3] = fmaf(av[i], bv.w, acc[i][3]);
    }
  }
  size_t n0 = (size_t)mt * 64;
#pragma unroll
  for (int i = 0; i < 4; ++i) {
    float4 st = make_float4(acc[i][0], acc[i][1], acc[i][2], acc[i][3]);
    *(float4*)&A0[(n0 + ty * 4 + i) * KDIM + nt * 64 + tx * 4] = st;
  }
}

// ---- fp32 solve, no pivoting (G_II near-identity), saved reciprocals ----
template <int SZ>
__device__ __forceinline__ void solve_sz(const float (&gs)[4][4], const float (&rhs)[4],
                                         float (&gamma)[4]) {
  float M[SZ][SZ];
  float y[SZ];
  float idg[SZ];
#pragma unroll
  for (int a = 0; a < SZ; ++a) {
    y[a] = rhs[a];
#pragma unroll
    for (int b = 0; b < SZ; ++b) M[a][b] = gs[a][b] + (a == b ? 1e-7f : 0.0f);
  }
#pragma unroll
  for (int p = 0; p < SZ; ++p) {
    float ip = __builtin_amdgcn_rcpf(M[p][p]);
    idg[p] = ip;
#pragma unroll
    for (int r = p + 1; r < SZ; ++r) {
      float f = M[r][p] * ip;
#pragma unroll
      for (int c = p + 1; c < SZ; ++c) M[r][c] = fmaf(-f, M[p][c], M[r][c]);
      y[r] = fmaf(-f, y[p], y[r]);
    }
  }
#pragma unroll
  for (int r = SZ - 1; r >= 0; --r) {
    float t = y[r];
#pragma unroll
    for (int c = r + 1; c < SZ; ++c) t = fmaf(-M[r][c], gamma[c], t);
    gamma[r] = t * idg[r];
  }
}

template <int K>
__device__ __forceinline__ void omp_step(int lane, int n, const float* __restrict__ G,
                                         const float* __restrict__ A0,
                                         float (&a0)[8], float (&al)[8], float (&Grow)[4][8],
                                         float (&gs)[4][4], float (&rhs)[4], int (&idx)[4],
                                         float (&gamma)[4]) {
  // ---- argmax |al| over all 512, first-occurrence (lowest k) wins ----
  // phase 1: float-only max (abs folds into v_max input modifier)
  float mx = fabsf(al[0]);
#pragma unroll
  for (int m = 1; m < 8; ++m) mx = fmaxf(mx, fabsf(al[m]));
#pragma unroll
  for (int off = 32; off >= 1; off >>= 1) mx = fmaxf(mx, __shfl_xor(mx, off));
  // phase 2: locate lowest k whose |al| equals the (bit-exact) max
  int mmask = 0;
#pragma unroll
  for (int m = 0; m < 8; ++m) mmask |= (fabsf(al[m]) == mx) ? (1 << m) : 0;
  unsigned long long ball = __ballot(mmask != 0);
  int srcl = (int)__builtin_ctzll(ball);           // lowest matching lane
  int bm = __builtin_ctz((unsigned)__shfl(mmask, srcl) | 0x100u);
  int sk = __builtin_amdgcn_readfirstlane(srcl * 8 + bm);  // wave-uniform SGPR
  idx[K] = sk;

  // full G row (vector load, for the alpha update)
  const float4* gp = (const float4*)(G + (size_t)sk * KDIM + lane * 8);
  float4 r0 = gp[0], r1 = gp[1];
  Grow[K][0] = r0.x; Grow[K][1] = r0.y; Grow[K][2] = r0.z; Grow[K][3] = r0.w;
  Grow[K][4] = r1.x; Grow[K][5] = r1.y; Grow[K][6] = r1.z; Grow[K][7] = r1.w;

  // G_sub and rhs entries via scalar loads (all-SGPR addresses, L2-resident)
  const float* grow_base = G + (size_t)sk * KDIM;
#pragma unroll
  for (int b = 0; b < K; ++b) {
    float v = grow_base[idx[b]];
    gs[K][b] = v;
    gs[b][K] = v;
  }
  gs[K][K] = grow_base[sk];
  rhs[K] = A0[(size_t)n * KDIM + sk];

  solve_sz<K + 1>(gs, rhs, gamma);

  if (K < 3) {
#pragma unroll
    for (int m = 0; m < 8; ++m) {
      float acc = a0[m];
#pragma unroll
      for (int a = 0; a <= K; ++a) acc = fmaf(-gamma[a], Grow[a][m], acc);
      al[m] = acc;
    }
  }
}

// ---- OMP main: one wave per signal ----
__global__ __launch_bounds__(256) void k_omp(const float* __restrict__ A0,
                                             const float* __restrict__ G,
                                             float4* __restrict__ wg, int4* __restrict__ wi) {
  int tid = threadIdx.x;
  int lane = tid & 63;
  int wv = __builtin_amdgcn_readfirstlane(tid >> 6);  // wave-uniform SGPR
  int n = blockIdx.x * 4 + wv;                        // grid = 8192 blocks
  const float4* ap = (const float4*)(A0 + (size_t)n * KDIM + lane * 8);
  float4 v0 = ap[0], v1 = ap[1];
  float a0[8] = {v0.x, v0.y, v0.z, v0.w, v1.x, v1.y, v1.z, v1.w};
  float al[8];
#pragma unroll
  for (int m = 0; m < 8; ++m) al[m] = a0[m];
  float Grow[4][8];
  float gs[4][4];
  float rhs[4];
  int idx[4];
  float gamma[4];
  omp_step<0>(lane, n, G, A0, a0, al, Grow, gs, rhs, idx, gamma);
  omp_step<1>(lane, n, G, A0, a0, al, Grow, gs, rhs, idx, gamma);
  omp_step<2>(lane, n, G, A0, a0, al, Grow, gs, rhs, idx, gamma);
  omp_step<3>(lane, n, G, A0, a0, al, Grow, gs, rhs, idx, gamma);
  // dedupe: scatter-set semantics — later slot with same index wins
  bool k0 = (idx[0] != idx[1]) && (idx[0] != idx[2]) && (idx[0] != idx[3]);
  bool k1 = (idx[1] != idx[2]) && (idx[1] != idx[3]);
  bool k2 = (idx[2] != idx[3]);
  if (lane == 0) {
    wg[n] = make_float4(k0 ? gamma[0] : 0.f, k1 ? gamma[1] : 0.f,
                        k2 ? gamma[2] : 0.f, gamma[3]);
    wi[n] = make_int4(idx[0], idx[1], idx[2], idx[3]);
  }
}

// ---- epilogue A: quant + diff + stats, per (b,h) row of 64 signals ----
__global__ __launch_bounds__(256) void k_epi(const float* __restrict__ X,
                                             const float* __restrict__ DnT,
                                             const float4* __restrict__ wg,
                                             const int4* __restrict__ wi,
                                             float* __restrict__ out, double* __restrict__ accs,
                                             int* __restrict__ hist) {
  __shared__ int sIdx[64][4];
  __shared__ float sKg[64][4];
  __shared__ float q[64 * 65];
  __shared__ float red[4];
  int tid = threadIdx.x;
  int bh = blockIdx.x;  // grid = 512
  int b = bh >> 6, h = bh & 63;

  if (tid < 64) {
    int w = tid;
    int n = bh * 64 + w;
    int4 iv = wi[n];
    float4 gv = wg[n];  // already deduped in k_omp
    sIdx[w][0] = iv.x; sIdx[w][1] = iv.y; sIdx[w][2] = iv.z; sIdx[w][3] = iv.w;
    sKg[w][0] = gv.x; sKg[w][1] = gv.y; sKg[w][2] = gv.z; sKg[w][3] = gv.w;
    int nz = (int)(gv.x != 0.f) + (int)(gv.y != 0.f) +
             (int)(gv.z != 0.f) + (int)(gv.w != 0.f);
    float s = fabsf(gv.x) + fabsf(gv.y) + fabsf(gv.z) + fabsf(gv.w);
#pragma unroll
    for (int off = 32; off >= 1; off >>= 1) s += __shfl_xor(s, off);
#pragma unroll
    for (int v = 0; v < 5; ++v) {
      unsigned long long m = __ballot(nz == v);
      if (tid == 0) {
        int c = (int)__popcll(m);
        if (c) atomicAdd(&hist[v], c);
      }
    }
    if (tid == 0) atomicAdd(&accs[1], (double)s);
  }
  __syncthreads();

  int w2 = tid & 63, p = tid >> 6, c0 = p * 16;
  float acc[16] = {};
#pragma unroll
  for (int s = 0; s < 4; ++s) {
    int ks = sIdx[w2][s];
    float g = sKg[w2][s];
    const float4* dp = (const float4*)(DnT + (size_t)ks * CDIM + c0);
#pragma unroll
    for (int i4 = 0; i4 < 4; ++i4) {
      float4 d = dp[i4];
      acc[i4 * 4 + 0] = fmaf(g, d.x, acc[i4 * 4 + 0]);
      acc[i4 * 4 + 1] = fmaf(g, d.y, acc[i4 * 4 + 1]);
      acc[i4 * 4 + 2] = fmaf(g, d.z, acc[i4 * 4 + 2]);
      acc[i4 * 4 + 3] = fmaf(g, d.w, acc[i4 * 4 + 3]);
    }
  }
#pragma unroll
  for (int i = 0; i < 16; ++i) q[(c0 + i) * 65 + w2] = acc[i];
  __syncthreads();

  float sumsq = 0.f;
#pragma unroll
  for (int pass = 0; pass < 16; ++pass) {
    int c = pass * 4 + p;
    float qv = q[c * 65 + w2];
    size_t off = (((size_t)b * CDIM + c) * HQ + h) * WQ + w2;
    float xv = X[off];
    float d = qv - xv;
    sumsq = fmaf(d, d, sumsq);
    out[off] = qv;
  }

#pragma unroll
  for (int off = 32; off >= 1; off >>= 1) sumsq += __shfl_xor(sumsq, off);
  if ((tid & 63) == 0) red[tid >> 6] = sumsq;
  __syncthreads();
  if (tid == 0) atomicAdd(&accs[2], (double)(red[0] + red[1] + red[2] + red[3]));
}

// ---- epilogue B: dense ids write, grid 2048 = (b,h) x k-quarter ----
__global__ __launch_bounds__(256) void k_ids(const float4* __restrict__ wg,
                                             const int4* __restrict__ wi,
                                             float* __restrict__ out) {
  __shared__ int4 sIdx[64];
  __shared__ float4 sKg[64];
  int tid = threadIdx.x;
  int bh = blockIdx.x >> 2, kq = blockIdx.x & 3;
  int b = bh >> 6, h = bh & 63;
  if (tid < 64) {
    int n = bh * 64 + tid;
    sIdx[tid] = wi[n];
    sKg[tid] = wg[n];
  }
  __syncthreads();
  int w = tid & 63, kp = tid >> 6;
  int4 iv = sIdx[w];
  float4 gv = sKg[w];
  int k0 = kq * 128 + kp * 32;
  float* ids = out + IDS_OFF;
  size_t base = (((size_t)b * KDIM + k0) * HQ + h) * WQ + w;
#pragma unroll
  for (int kk = 0; kk < 32; ++kk) {
    int k = k0 + kk;
    float v = 0.f;
    v = (k == iv.x) ? gv.x : v;
    v = (k == iv.y) ? gv.y : v;
    v = (k == iv.z) ? gv.z : v;
    v = (k == iv.w) ? gv.w : v;
    ids[base + (size_t)kk * HQ * WQ] = v;
  }
}

// ---- finalize scalars ----
__global__ __launch_bounds__(64) void k_final(const double* __restrict__ accs,
                                              const int* __restrict__ hist,
                                              float* __restrict__ out) {
  if (threadIdx.x == 0) {
    double sumAbsD = accs[0], sumAbsZ = accs[1], sumSq = accs[2];
    float diff = (float)(sumSq / 2097152.0);
    out[DIFF_ENC_OFF] = diff;
    out[DIFF_DICT_OFF] = diff;
    out[NUM_STEPS_OFF] = 4.0f;
    out[MEAN_D_OFF] = (float)(sumAbsD / 32768.0);
    out[MEAN_Z_OFF] = (float)(sumAbsZ / 16777216.0);
    int h0 = hist[0], h1 = hist[1], h2 = hist[2], h3 = hist[3], h4 = hist[4];
    out[NORM_Z_OFF] = (float)((double)(h1 + 2 * h2 + 3 * h3 + 4 * h4) / 32768.0);
    int cum = 0, res = 0;
    for (int v = 4; v >= 0; --v) {
      cum += hist[v];
      if (cum >= 327) { res = v; break; }
    }
    out[TOP_PCT_OFF] = (float)res;
    out[NUM_ZEROS_OFF] = (float)h0;
  }
}

extern "C" void kernel_launch(void* const* d_in, const int* in_sizes, int n_in,
                              void* d_out, int out_size, void* d_ws, size_t ws_size,
                              hipStream_t stream) {
  (void)in_sizes; (void)n_in; (void)out_size; (void)ws_size;
  const float* X = (const float*)d_in[0];    // [8,64,64,64]
  const float* D = (const float*)d_in[1];    // [64,512]
  float* out = (float*)d_out;
  float* W = (float*)d_ws;
  double* accs = (double*)d_ws;
  int* hist = (int*)W + 8;
  float* Dn = W + WS_DN;
  float* DnT = W + WS_DNT;
  float* G = W + WS_G;
  float4* wgam = (float4*)(W + WS_WG);
  int4* widx = (int4*)(W + WS_WI);
  float* A0 = out;  // stage alpha0 in d_out[0 .. 16,777,216) — overwritten later

  hipLaunchKernelGGL(k_dict, dim3(1), dim3(512), 0, stream, D, Dn, DnT, W);
  hipLaunchKernelGGL(k_gram, dim3(1024), dim3(256), 0, stream, Dn, G);
  hipLaunchKernelGGL(k_alpha0, dim3(4096), dim3(256), 0, stream, X, Dn, A0);
  hipLaunchKernelGGL(k_omp, dim3(8192), dim3(256), 0, stream, A0, G, wgam, widx);
  hipLaunchKernelGGL(k_epi, dim3(512), dim3(256), 0, stream, X, DnT, wgam, widx, out, accs, hist);
  hipLaunchKernelGGL(k_ids, dim3(2048), dim3(256), 0, stream, wgam, widx, out);
  hipLaunchKernelGGL(k_final, dim3(1), dim3(64), 0, stream, accs, hist, out);
}

// Round 3
// 171.671 us; speedup vs baseline: 1.1928x; 1.1078x over previous
//
#include <hip/hip_runtime.h>
#include <cstdint>
#include <cstddef>

// Problem constants
#define BQ 8
#define CDIM 64
#define HQ 64
#define WQ 64
#define KDIM 512
#define N_SIG 32768   // B*H*W
#define S_NNZ 4

// d_out float offsets (outputs concatenated flat in return order)
#define DIFF_ENC_OFF 2097152
#define DIFF_DICT_OFF 2097153
#define IDS_OFF 2097154
#define NUM_STEPS_OFF 18874370
#define MEAN_D_OFF 18874371
#define MEAN_Z_OFF 18874372
#define NORM_Z_OFF 18874373
#define TOP_PCT_OFF 18874374
#define NUM_ZEROS_OFF 18874375

// ws float offsets
// [0..4)   : accs[2] doubles: sumAbsZ, sumSq   (zeroed by k_ga block 0)
// [4..9)   : hist[5] ints                      (zeroed by k_ga block 0)
// [16..24) : pd[8] per-block |Dn| partial sums (written by k_dict, no atomics)
#define WS_PD 16
#define WS_DN 32
#define WS_DNT 32800
#define WS_G 65568
#define WS_WG 327712   // float4 per signal (deduped gamma)
#define WS_WI 458784   // int4 per signal (idx)

typedef float v2f __attribute__((ext_vector_type(2)));

// ---- dictionary normalization: 8 blocks x 64 threads, one column each ----
__global__ __launch_bounds__(64) void k_dict(const float* __restrict__ D,
                                             float* __restrict__ Dn,
                                             float* __restrict__ DnT,
                                             float* __restrict__ pd) {
  int tid = threadIdx.x;
  int k = blockIdx.x * 64 + tid;
  float ss = 0.f;
  for (int c = 0; c < CDIM; ++c) {
    float v = D[c * KDIM + k];
    ss = fmaf(v, v, ss);
  }
  float nrm = sqrtf(ss);
  float sabs = 0.f;
  for (int c = 0; c < CDIM; ++c) {
    float v = D[c * KDIM + k] / nrm;
    Dn[c * KDIM + k] = v;
    DnT[k * CDIM + c] = v;
    sabs += fabsf(v);
  }
#pragma unroll
  for (int off = 32; off >= 1; off >>= 1) sabs += __shfl_xor(sabs, off);
  if (tid == 0) pd[blockIdx.x] = sabs;
}

// ---- fused: G = Dn^T Dn (blocks 0..63) + alpha0 = X@Dn (blocks 64..4159) ----
__global__ __launch_bounds__(256) void k_ga(const float* __restrict__ X,
                                            const float* __restrict__ Dn,
                                            float* __restrict__ A0,
                                            float* __restrict__ G,
                                            float* __restrict__ W) {
  __shared__ float Xs[64 * 65];   // alpha0: X tile (padded); gram: DnI tile (64-stride)
  __shared__ float Dns[64 * 64];
  int tid = threadIdx.x;
  int w = tid & 63, cq = tid >> 6;
  int ty = tid >> 4, tx = tid & 15;

  if (blockIdx.x < 64) {
    // ---------------- Gram tile (ti,tj) of 64x64 ----------------
    if (blockIdx.x == 0 && tid < 16) ((unsigned int*)W)[tid] = 0u;  // accs+hist zero
    int ti = blockIdx.x >> 3, tj = blockIdx.x & 7;
#pragma unroll
    for (int p = 0; p < 16; ++p) {
      int c = p * 4 + cq;
      Xs[c * 64 + w] = Dn[(size_t)c * KDIM + ti * 64 + w];
      Dns[c * 64 + w] = Dn[(size_t)c * KDIM + tj * 64 + w];
    }
    __syncthreads();
    v2f acc[4][2] = {};
    for (int c = 0; c < 64; ++c) {
      float av[4];
#pragma unroll
      for (int i = 0; i < 4; ++i) av[i] = Xs[c * 64 + ty * 4 + i];
      float4 bv = *(const float4*)&Dns[c * 64 + tx * 4];
      v2f b0 = {bv.x, bv.y}, b1 = {bv.z, bv.w};
#pragma unroll
      for (int i = 0; i < 4; ++i) {
        v2f a2 = {av[i], av[i]};
        acc[i][0] = __builtin_elementwise_fma(a2, b0, acc[i][0]);
        acc[i][1] = __builtin_elementwise_fma(a2, b1, acc[i][1]);
      }
    }
#pragma unroll
    for (int i = 0; i < 4; ++i) {
      float4 st = make_float4(acc[i][0].x, acc[i][0].y, acc[i][1].x, acc[i][1].y);
      *(float4*)&G[(size_t)(ti * 64 + ty * 4 + i) * KDIM + tj * 64 + tx * 4] = st;
    }
  } else {
    // ---------------- alpha0 tile: 64 signals x 64 atoms ----------------
    int bb = blockIdx.x - 64;
    int mt = bb >> 3, nt = bb & 7;
    int b = mt >> 6, h = mt & 63;
#pragma unroll
    for (int p = 0; p < 16; ++p) {
      int c = p * 4 + cq;
      Xs[w * 65 + c] = X[(((size_t)b * CDIM + c) * HQ + h) * WQ + w];
      Dns[c * 64 + w] = Dn[(size_t)c * KDIM + nt * 64 + w];
    }
    __syncthreads();
    v2f acc[4][2] = {};
    for (int c = 0; c < 64; ++c) {
      float av[4];
#pragma unroll
      for (int i = 0; i < 4; ++i) av[i] = Xs[(ty * 4 + i) * 65 + c];
      float4 bv = *(const float4*)&Dns[c * 64 + tx * 4];
      v2f b0 = {bv.x, bv.y}, b1 = {bv.z, bv.w};
#pragma unroll
      for (int i = 0; i < 4; ++i) {
        v2f a2 = {av[i], av[i]};
        acc[i][0] = __builtin_elementwise_fma(a2, b0, acc[i][0]);
        acc[i][1] = __builtin_elementwise_fma(a2, b1, acc[i][1]);
      }
    }
    size_t n0 = (size_t)mt * 64;
#pragma unroll
    for (int i = 0; i < 4; ++i) {
      float4 st = make_float4(acc[i][0].x, acc[i][0].y, acc[i][1].x, acc[i][1].y);
      *(float4*)&A0[(n0 + ty * 4 + i) * KDIM + nt * 64 + tx * 4] = st;
    }
  }
}

// ---- fp32 solve, no pivoting (G_II near-identity), saved reciprocals ----
template <int SZ>
__device__ __forceinline__ void solve_sz(const float (&gs)[4][4], const float (&rhs)[4],
                                         float (&gamma)[4]) {
  float M[SZ][SZ];
  float y[SZ];
  float idg[SZ];
#pragma unroll
  for (int a = 0; a < SZ; ++a) {
    y[a] = rhs[a];
#pragma unroll
    for (int b = 0; b < SZ; ++b) M[a][b] = gs[a][b] + (a == b ? 1e-7f : 0.0f);
  }
#pragma unroll
  for (int p = 0; p < SZ; ++p) {
    float ip = __builtin_amdgcn_rcpf(M[p][p]);
    idg[p] = ip;
#pragma unroll
    for (int r = p + 1; r < SZ; ++r) {
      float f = M[r][p] * ip;
#pragma unroll
      for (int c = p + 1; c < SZ; ++c) M[r][c] = fmaf(-f, M[p][c], M[r][c]);
      y[r] = fmaf(-f, y[p], y[r]);
    }
  }
#pragma unroll
  for (int r = SZ - 1; r >= 0; --r) {
    float t = y[r];
#pragma unroll
    for (int c = r + 1; c < SZ; ++c) t = fmaf(-M[r][c], gamma[c], t);
    gamma[r] = t * idg[r];
  }
}

template <int K>
__device__ __forceinline__ void omp_step(int lane, int n, const float* __restrict__ G,
                                         const float* __restrict__ A0,
                                         float (&a0)[8], float (&al)[8], float (&Grow)[3][8],
                                         float (&gs)[4][4], float (&rhs)[4], int (&idx)[4],
                                         float (&gamma)[4]) {
  // ---- argmax |al| over 512, first-occurrence (lowest k) wins ----
  // phase 1: float-only max butterfly (abs folds into v_max modifiers)
  float mx = fabsf(al[0]);
#pragma unroll
  for (int m = 1; m < 8; ++m) mx = fmaxf(mx, fabsf(al[m]));
#pragma unroll
  for (int off = 32; off >= 1; off >>= 1) mx = fmaxf(mx, __shfl_xor(mx, off));
  // phase 2: per-m ballot + SALU min (k = lane*8 + m; lowest k wins)
  int sk = 1 << 30;
#pragma unroll
  for (int m = 0; m < 8; ++m) {
    unsigned long long bm = __ballot(fabsf(al[m]) == mx);
    if (bm) {
      int kk = (int)__builtin_ctzll(bm) * 8 + m;
      sk = kk < sk ? kk : sk;
    }
  }
  idx[K] = sk;  // wave-uniform (derived from ballots)

  const float* grow_base = G + (size_t)sk * KDIM;
  if constexpr (K < 3) {
    // full G row (vector load) — needed only for the alpha update
    const float4* gp = (const float4*)(grow_base + lane * 8);
    float4 r0 = gp[0], r1 = gp[1];
    Grow[K][0] = r0.x; Grow[K][1] = r0.y; Grow[K][2] = r0.z; Grow[K][3] = r0.w;
    Grow[K][4] = r1.x; Grow[K][5] = r1.y; Grow[K][6] = r1.z; Grow[K][7] = r1.w;
  }

  // G_sub and rhs entries via scalar loads (all-SGPR addresses, L2-resident)
#pragma unroll
  for (int b = 0; b < K; ++b) {
    float v = grow_base[idx[b]];
    gs[K][b] = v;
    gs[b][K] = v;
  }
  gs[K][K] = grow_base[sk];
  rhs[K] = A0[(size_t)n * KDIM + sk];

  solve_sz<K + 1>(gs, rhs, gamma);

  if constexpr (K < 3) {
#pragma unroll
    for (int m = 0; m < 8; ++m) {
      float acc = a0[m];
#pragma unroll
      for (int a = 0; a <= K; ++a) acc = fmaf(-gamma[a], Grow[a][m], acc);
      al[m] = acc;
    }
  }
}

// ---- OMP main: one wave per signal ----
__global__ __launch_bounds__(256) void k_omp(const float* __restrict__ A0,
                                             const float* __restrict__ G,
                                             float4* __restrict__ wg, int4* __restrict__ wi) {
  int tid = threadIdx.x;
  int lane = tid & 63;
  int wv = __builtin_amdgcn_readfirstlane(tid >> 6);
  int n = blockIdx.x * 4 + wv;  // grid = 8192 blocks
  const float4* ap = (const float4*)(A0 + (size_t)n * KDIM + lane * 8);
  float4 v0 = ap[0], v1 = ap[1];
  float a0[8] = {v0.x, v0.y, v0.z, v0.w, v1.x, v1.y, v1.z, v1.w};
  float al[8];
#pragma unroll
  for (int m = 0; m < 8; ++m) al[m] = a0[m];
  float Grow[3][8];
  float gs[4][4];
  float rhs[4];
  int idx[4];
  float gamma[4];
  omp_step<0>(lane, n, G, A0, a0, al, Grow, gs, rhs, idx, gamma);
  omp_step<1>(lane, n, G, A0, a0, al, Grow, gs, rhs, idx, gamma);
  omp_step<2>(lane, n, G, A0, a0, al, Grow, gs, rhs, idx, gamma);
  omp_step<3>(lane, n, G, A0, a0, al, Grow, gs, rhs, idx, gamma);
  // dedupe: scatter-set semantics — later slot with same index wins
  bool k0 = (idx[0] != idx[1]) && (idx[0] != idx[2]) && (idx[0] != idx[3]);
  bool k1 = (idx[1] != idx[2]) && (idx[1] != idx[3]);
  bool k2 = (idx[2] != idx[3]);
  if (lane == 0) {
    wg[n] = make_float4(k0 ? gamma[0] : 0.f, k1 ? gamma[1] : 0.f,
                        k2 ? gamma[2] : 0.f, gamma[3]);
    wi[n] = make_int4(idx[0], idx[1], idx[2], idx[3]);
  }
}

// ---- fused epilogue: blocks 0..511 quant+stats, blocks 512..2559 dense ids ----
__global__ __launch_bounds__(256) void k_ei(const float* __restrict__ X,
                                            const float* __restrict__ DnT,
                                            const float4* __restrict__ wg,
                                            const int4* __restrict__ wi,
                                            float* __restrict__ out, double* __restrict__ accs,
                                            int* __restrict__ hist) {
  __shared__ __align__(16) int sIdx[64][4];
  __shared__ __align__(16) float sKg[64][4];
  __shared__ float q[64 * 65];
  __shared__ float red[4];
  int tid = threadIdx.x;

  if (blockIdx.x < 512) {
    int bh = blockIdx.x;
    int b = bh >> 6, h = bh & 63;
    if (tid < 64) {
      int w = tid;
      int n = bh * 64 + w;
      int4 iv = wi[n];
      float4 gv = wg[n];  // already deduped in k_omp
      sIdx[w][0] = iv.x; sIdx[w][1] = iv.y; sIdx[w][2] = iv.z; sIdx[w][3] = iv.w;
      sKg[w][0] = gv.x; sKg[w][1] = gv.y; sKg[w][2] = gv.z; sKg[w][3] = gv.w;
      int nz = (int)(gv.x != 0.f) + (int)(gv.y != 0.f) +
               (int)(gv.z != 0.f) + (int)(gv.w != 0.f);
      float s = fabsf(gv.x) + fabsf(gv.y) + fabsf(gv.z) + fabsf(gv.w);
#pragma unroll
      for (int off = 32; off >= 1; off >>= 1) s += __shfl_xor(s, off);
#pragma unroll
      for (int v = 0; v < 5; ++v) {
        unsigned long long m = __ballot(nz == v);
        if (tid == 0) {
          int c = (int)__popcll(m);
          if (c) atomicAdd(&hist[v], c);
        }
      }
      if (tid == 0) atomicAdd(&accs[0], (double)s);
    }
    __syncthreads();

    int w2 = tid & 63, p = tid >> 6, c0 = p * 16;
    float acc[16] = {};
#pragma unroll
    for (int s = 0; s < 4; ++s) {
      int ks = sIdx[w2][s];
      float g = sKg[w2][s];
      const float4* dp = (const float4*)(DnT + (size_t)ks * CDIM + c0);
#pragma unroll
      for (int i4 = 0; i4 < 4; ++i4) {
        float4 d = dp[i4];
        acc[i4 * 4 + 0] = fmaf(g, d.x, acc[i4 * 4 + 0]);
        acc[i4 * 4 + 1] = fmaf(g, d.y, acc[i4 * 4 + 1]);
        acc[i4 * 4 + 2] = fmaf(g, d.z, acc[i4 * 4 + 2]);
        acc[i4 * 4 + 3] = fmaf(g, d.w, acc[i4 * 4 + 3]);
      }
    }
#pragma unroll
    for (int i = 0; i < 16; ++i) q[(c0 + i) * 65 + w2] = acc[i];
    __syncthreads();

    float sumsq = 0.f;
#pragma unroll
    for (int pass = 0; pass < 16; ++pass) {
      int c = pass * 4 + p;
      float qv = q[c * 65 + w2];
      size_t off = (((size_t)b * CDIM + c) * HQ + h) * WQ + w2;
      float xv = X[off];
      float d = qv - xv;
      sumsq = fmaf(d, d, sumsq);
      out[off] = qv;
    }

#pragma unroll
    for (int off = 32; off >= 1; off >>= 1) sumsq += __shfl_xor(sumsq, off);
    if ((tid & 63) == 0) red[tid >> 6] = sumsq;
    __syncthreads();
    if (tid == 0) atomicAdd(&accs[1], (double)(red[0] + red[1] + red[2] + red[3]));
  } else {
    // ---------------- dense ids write ----------------
    int bid = blockIdx.x - 512;
    int bh = bid >> 2, kq = bid & 3;
    int b = bh >> 6, h = bh & 63;
    if (tid < 64) {
      int n = bh * 64 + tid;
      *(int4*)&sIdx[tid][0] = wi[n];
      *(float4*)&sKg[tid][0] = wg[n];
    }
    __syncthreads();
    int w = tid & 63, kp = tid >> 6;
    int4 iv = *(int4*)&sIdx[w][0];
    float4 gv = *(float4*)&sKg[w][0];
    int k0 = kq * 128 + kp * 32;
    float* ids = out + IDS_OFF;
    size_t base = (((size_t)b * KDIM + k0) * HQ + h) * WQ + w;
#pragma unroll
    for (int kk = 0; kk < 32; ++kk) {
      int k = k0 + kk;
      float v = 0.f;
      v = (k == iv.x) ? gv.x : v;
      v = (k == iv.y) ? gv.y : v;
      v = (k == iv.z) ? gv.z : v;
      v = (k == iv.w) ? gv.w : v;
      ids[base + (size_t)kk * HQ * WQ] = v;
    }
  }
}

// ---- finalize scalars ----
__global__ __launch_bounds__(64) void k_final(const double* __restrict__ accs,
                                              const int* __restrict__ hist,
                                              const float* __restrict__ pd,
                                              float* __restrict__ out) {
  if (threadIdx.x == 0) {
    float sumAbsD = 0.f;
#pragma unroll
    for (int i = 0; i < 8; ++i) sumAbsD += pd[i];
    double sumAbsZ = accs[0], sumSq = accs[1];
    float diff = (float)(sumSq / 2097152.0);
    out[DIFF_ENC_OFF] = diff;
    out[DIFF_DICT_OFF] = diff;
    out[NUM_STEPS_OFF] = 4.0f;
    out[MEAN_D_OFF] = sumAbsD / 32768.0f;
    out[MEAN_Z_OFF] = (float)(sumAbsZ / 16777216.0);
    int h0 = hist[0], h1 = hist[1], h2 = hist[2], h3 = hist[3], h4 = hist[4];
    out[NORM_Z_OFF] = (float)((double)(h1 + 2 * h2 + 3 * h3 + 4 * h4) / 32768.0);
    int cum = 0, res = 0;
    for (int v = 4; v >= 0; --v) {
      cum += hist[v];
      if (cum >= 327) { res = v; break; }
    }
    out[TOP_PCT_OFF] = (float)res;
    out[NUM_ZEROS_OFF] = (float)h0;
  }
}

extern "C" void kernel_launch(void* const* d_in, const int* in_sizes, int n_in,
                              void* d_out, int out_size, void* d_ws, size_t ws_size,
                              hipStream_t stream) {
  (void)in_sizes; (void)n_in; (void)out_size; (void)ws_size;
  const float* X = (const float*)d_in[0];    // [8,64,64,64]
  const float* D = (const float*)d_in[1];    // [64,512]
  float* out = (float*)d_out;
  float* W = (float*)d_ws;
  double* accs = (double*)d_ws;
  int* hist = (int*)W + 4;
  float* pd = W + WS_PD;
  float* Dn = W + WS_DN;
  float* DnT = W + WS_DNT;
  float* G = W + WS_G;
  float4* wgam = (float4*)(W + WS_WG);
  int4* widx = (int4*)(W + WS_WI);
  float* A0 = out;  // stage alpha0 in d_out[0 .. 16,777,216) — overwritten later

  hipLaunchKernelGGL(k_dict, dim3(8), dim3(64), 0, stream, D, Dn, DnT, pd);
  hipLaunchKernelGGL(k_ga, dim3(4160), dim3(256), 0, stream, X, Dn, A0, G, W);
  hipLaunchKernelGGL(k_omp, dim3(8192), dim3(256), 0, stream, A0, G, wgam, widx);
  hipLaunchKernelGGL(k_ei, dim3(2560), dim3(256), 0, stream, X, DnT, wgam, widx, out, accs, hist);
  hipLaunchKernelGGL(k_final, dim3(1), dim3(64), 0, stream, accs, hist, pd, out);
}